// Round 8
// baseline (125.347 us; speedup 1.0000x reference)
//
#include <hip/hip_runtime.h>

#define NPARC 289
#define NOUT  578
#define DIMK  512
#define BATCH 32768

typedef __bf16 bf16x8 __attribute__((ext_vector_type(8)));
typedef float floatx16 __attribute__((ext_vector_type(16)));

__device__ __forceinline__ unsigned short f2bf(float f) {
    unsigned u = __float_as_uint(f);
    u = (u + 0x7fffu + ((u >> 16) & 1u)) >> 16;
    return (unsigned short)u;
}

// ROUND 14 prep: 32x32x16 A-operand layout (verified numerically in R4) +
// re/im slot interleave (verified in R5). slot 2j = W row j (re), slot
// 2j+1 = W row j+289 (im). Fragment: m = t*32 + (lane&31),
// k = ks*16 + (lane>>5)*8 + j. Slots >= 578 zero-filled.
__global__ void prep_w(const float* __restrict__ W, unsigned short* __restrict__ Wp) {
    int wid = threadIdx.x >> 6;
    int lane = threadIdx.x & 63;
    int slot = blockIdx.x * 4 + wid;         // [0, 640)
    int k = lane * 8;                        // [0, 512)
    unsigned short v[8];
    if (slot < NOUT) {
        int o = (slot & 1) ? NPARC + (slot >> 1) : (slot >> 1);
        const float* src = W + (size_t)o * DIMK + k;
        #pragma unroll
        for (int j = 0; j < 8; ++j) v[j] = f2bf(src[j]);
    } else {
        #pragma unroll
        for (int j = 0; j < 8; ++j) v[j] = 0;
    }
    int t    = slot >> 5;
    int ks   = lane >> 1;        // k/16
    int half = lane & 1;         // (k/8)&1
    int ln   = half * 32 + (slot & 31);
    uint4 o4;
    o4.x = (unsigned)v[0] | ((unsigned)v[1] << 16);
    o4.y = (unsigned)v[2] | ((unsigned)v[3] << 16);
    o4.z = (unsigned)v[4] | ((unsigned)v[5] << 16);
    o4.w = (unsigned)v[6] | ((unsigned)v[7] << 16);
    *(uint4*)(Wp + (size_t)((t * 32 + ks) * 64 + ln) * 8) = o4;
}

// ROUND 14: slim 32x32 K-loop + K-rotation decorrelation.
// Cross-round evidence: occupancy (18 vs 38%), barriers (R2 ~none vs R7
// per-slab), bank conflicts (786k vs 0) all DON'T move the 41-46us time;
// MfmaUtil pinned at ~19% because all resident waves stall on the same
// latency at the same time (lockstep code). Changes:
//  - 32x32x16 MFMA (R4-verified layout): per KS = 5 aw + 1 ds_read + 5
//    MFMA (388 cyc) — non-MFMA instr count per MFMA cycle drops ~3x.
//  - bf16 LDS (64 KB, reg-staged once, chunk^(row&15) swizzle both sides):
//    halves LDS bytes, no cvt in loop, 2 blocks/CU possible.
//  - ONE barrier total; 32-KS loop barrier-free.
//  - K-rotation: col-group cg starts at ks0 = cg*8, wraps mod 32 (sum is
//    order-invariant). 4 groups at 4 phases -> one group's MFMA burst
//    covers another's L2 wait. sg-twins stay in phase (Wp stays 640
//    KB/block; L1 catches the twin's repeat read).
//  - depth-1 ping-pong aw/bs + sched_barrier(0) + setprio on MFMA cluster.
__global__ __launch_bounds__(512, 3) void fused_kernel(
    const float* __restrict__ inputs, const float* __restrict__ targets,
    const float* __restrict__ bias, const unsigned short* __restrict__ Wp,
    float* __restrict__ out)
{
    __shared__ __align__(16) unsigned short buf[64 * 512];   // 64 KiB bf16
    __shared__ float R[8][32][3];                            // 3 KiB
    const int tid  = threadIdx.x;
    const int base = blockIdx.x * 64;
    const int wid  = tid >> 6;
    const int lane = tid & 63;
    const int sg   = wid >> 2;           // sample half (32 samples)
    const int cg   = wid & 3;            // col group (5 tiles of 32 = 160)
    const int hi   = lane >> 5;
    const int l31  = lane & 31;
    const int srow = sg * 32 + l31;      // this lane's LDS row (B-op sample)
    const int s15  = srow & 15;

    // ---- stage once: 8 chunk-rounds/thread, bf16, swizzled ----
    // chunk C = i*512+tid: row s=C>>6 (wave-uniform), logical chunk L=C&63
    // (8 bf16 = 16B), phys = L ^ (s&15). Src: 8 consecutive fp32.
    #pragma unroll
    for (int i = 0; i < 8; ++i) {
        int C = i * 512 + tid;
        int s = C >> 6;
        int L = C & 63;
        const float4* g = (const float4*)(inputs + (size_t)(base + s) * DIMK + L * 8);
        float4 a = g[0], b = g[1];
        union { __bf16 h[8]; uint4 u; } cv;
        cv.h[0] = (__bf16)a.x; cv.h[1] = (__bf16)a.y;
        cv.h[2] = (__bf16)a.z; cv.h[3] = (__bf16)a.w;
        cv.h[4] = (__bf16)b.x; cv.h[5] = (__bf16)b.y;
        cv.h[6] = (__bf16)b.z; cv.h[7] = (__bf16)b.w;
        *(uint4*)&buf[(size_t)(s * 64 + (L ^ (s & 15))) * 8] = cv.u;
    }
    __syncthreads();                     // the kernel's ONLY full barrier

#define LDAW(dst, ks)                                                         \
    { _Pragma("unroll") for (int t5_ = 0; t5_ < 5; ++t5_)                     \
        dst[t5_] = Wf[((size_t)(cg * 5 + t5_) * 32 + (ks)) * 64 + lane]; }

#define LDBS(ks)                                                              \
    (*(const bf16x8*)&buf[(size_t)(srow * 64 + (((ks) * 2 + hi) ^ s15)) * 8])

#define MFMA5(aww, bss)                                                       \
    __builtin_amdgcn_sched_barrier(0);                                        \
    __builtin_amdgcn_s_setprio(1);                                            \
    { _Pragma("unroll") for (int t5_ = 0; t5_ < 5; ++t5_)                     \
        acc[t5_] = __builtin_amdgcn_mfma_f32_32x32x16_bf16(                   \
            aww[t5_], bss, acc[t5_], 0, 0, 0); }                              \
    __builtin_amdgcn_s_setprio(0);                                            \
    __builtin_amdgcn_sched_barrier(0);

    const bf16x8* Wf = (const bf16x8*)Wp;
    floatx16 acc[5];
    #pragma unroll
    for (int t5 = 0; t5 < 5; ++t5) acc[t5] = (floatx16)0.f;

    const int ks0 = cg * 8;              // rotation: 4 groups, 4 phases

    bf16x8 awA[5], awB[5], bsA, bsB;
    LDAW(awA, ks0);
    bsA = LDBS(ks0);

    #pragma unroll
    for (int i = 0; i < 32; i += 2) {
        const int k1 = (ks0 + i + 1) & 31;
        LDAW(awB, k1);
        bsB = LDBS(k1);
        MFMA5(awA, bsA);
        if (i + 2 < 32) {
            const int k2 = (ks0 + i + 2) & 31;
            LDAW(awA, k2);
            bsA = LDBS(k2);
        }
        MFMA5(awB, bsB);
    }

    // ---- epilogue: q-pairs (rows 2q,2q+1 of C = re/im slots) ----
    // C/D map (R4-verified): col = lane&31, row = (reg&3)+8*(reg>>2)+4*hi
    float2 t2 = *(const float2*)(targets + 2 * (base + srow));
    float xs = 0.5f * t2.x;              // revolutions: sin(pi*z)=v_sin(z/2)
    float ys = 0.5f * t2.y;

    float pd = 0.f, pr = 0.f, pim = 0.f;

    #pragma unroll
    for (int t5 = 0; t5 < 5; ++t5)
        #pragma unroll
        for (int q = 0; q < 8; ++q) {
            int rq = ((2 * q) & 3) + 8 * ((2 * q) >> 2);   // 0,2,8,10,16,18,24,26
            int slot = (cg * 5 + t5) * 32 + rq + 4 * hi;   // even slot
            if (slot < NOUT) {
                int j = slot >> 1;
                int r = j / 17;
                int c = j - r * 17;
                float ve = acc[t5][2 * q]     + bias[j];
                float vo = acc[t5][2 * q + 1] + bias[j + NPARC];
                float u = fmaf((float)c, xs, (float)r * ys);
                u = __builtin_amdgcn_fractf(u);
                float sn = __builtin_amdgcn_sinf(u);
                float cs = __builtin_amdgcn_cosf(u);
                pd  = fmaf(ve, ve, pd);
                pd  = fmaf(vo, vo, pd);
                pr  = fmaf(ve, cs, pr);
                pr  = fmaf(-vo, sn, pr);
                pim = fmaf(ve, sn, pim);
                pim = fmaf(vo, cs, pim);
            }
        }

    // lanes l and l+32: same sample, disjoint C-rows -> fold halves
    pd  += __shfl_xor(pd, 32, 64);
    pr  += __shfl_xor(pr, 32, 64);
    pim += __shfl_xor(pim, 32, 64);

    if (lane < 32) {
        R[wid][l31][0] = pd;
        R[wid][l31][1] = pr;
        R[wid][l31][2] = pim;
    }
    __syncthreads();

    if (tid < 64) {
        int sgg = tid >> 5;
        int idx = tid & 31;
        float sd = 0.f, sr = 0.f, si = 0.f;
        #pragma unroll
        for (int c4 = 0; c4 < 4; ++c4) {   // wid = sg*4 + cg
            sd += R[sgg * 4 + c4][idx][0];
            sr += R[sgg * 4 + c4][idx][1];
            si += R[sgg * 4 + c4][idx][2];
        }
        out[base + tid] = (sr * sr + si * si) / (4.0f * sd);
    }
#undef LDAW
#undef LDBS
#undef MFMA5
}

extern "C" void kernel_launch(void* const* d_in, const int* in_sizes, int n_in,
                              void* d_out, int out_size, void* d_ws, size_t ws_size,
                              hipStream_t stream) {
    const float* inputs  = (const float*)d_in[0];
    const float* targets = (const float*)d_in[1];
    const float* W       = (const float*)d_in[2];
    const float* bias    = (const float*)d_in[3];
    unsigned short* Wp   = (unsigned short*)d_ws;   // 640 KiB of ws

    prep_w<<<160, 256, 0, stream>>>(W, Wp);
    fused_kernel<<<BATCH / 64, 512, 0, stream>>>(inputs, targets, bias, Wp, (float*)d_out);
}

// Round 9
// 115.317 us; speedup vs baseline: 1.0870x; 1.0870x over previous
//
#include <hip/hip_runtime.h>

#define NPARC 289
#define NOUT  578
#define DIMK  512
#define BATCH 32768

typedef __bf16 bf16x8 __attribute__((ext_vector_type(8)));
typedef float floatx4 __attribute__((ext_vector_type(4)));

__device__ __forceinline__ unsigned short f2bf(float f) {
    unsigned u = __float_as_uint(f);
    u = (u + 0x7fffu + ((u >> 16) & 1u)) >> 16;
    return (unsigned short)u;
}

// prep (verified R5/R7): INTERLEAVED col slots — slot 2j = re col j, slot
// 2j+1 = im col j (W row j+289) so the epilogue shares one sincos per
// (re,im) pair. 16x16x32 A-operand fragment order:
// m = ct*16 + (lane&15), k = ks*32 + (lane>>4)*8 + j. Slots >= 578 zero.
__global__ void prep_w(const float* __restrict__ W, unsigned short* __restrict__ Wp) {
    int wid = threadIdx.x >> 6;
    int lane = threadIdx.x & 63;
    int slot = blockIdx.x * 4 + wid;         // [0, 640)
    int k = lane * 8;
    unsigned short v[8];
    if (slot < NOUT) {
        int o = (slot & 1) ? NPARC + (slot >> 1) : (slot >> 1);
        const float* src = W + (size_t)o * DIMK + k;
        #pragma unroll
        for (int j = 0; j < 8; ++j) v[j] = f2bf(src[j]);
    } else {
        #pragma unroll
        for (int j = 0; j < 8; ++j) v[j] = 0;
    }
    int ct = slot >> 4;
    int ks = k >> 5;
    int ln = (((k >> 3) & 3) << 4) + (slot & 15);
    uint4 o4;
    o4.x = (unsigned)v[0] | ((unsigned)v[1] << 16);
    o4.y = (unsigned)v[2] | ((unsigned)v[3] << 16);
    o4.z = (unsigned)v[4] | ((unsigned)v[5] << 16);
    o4.w = (unsigned)v[6] | ((unsigned)v[7] << 16);
    *(uint4*)(Wp + (size_t)((ct * 16 + ks) * 64 + ln) * 8) = o4;
}

// ROUND 15: R7 (best, 40.9us) + three surgical changes.
// R8 post-mortem: aw:MFMA went 1:4 -> 1:1, quadrupling the 1KB-per-instr
// weight stream through the L1 path (~64 B/cy/CU) -> regression. aw traffic
// is algebraically floored at 335 MB total (st_w <= 4 given acc=80/thread
// forced); R7's geometry was already optimal. R7's remaining fat:
//  1. fp32-in-LDS doubled DS-read bytes (8 b128/KS) and paid 32 cvts/KS in
//     the loop. Now: bf16 LDS (16 KB/slab) via T14 split reg-staging —
//     g-loads at slab top, cvt_pk + ds_write_b128 at slab end (auto-wait
//     on g is counted; aw stream unaffected). 4 b128/KS, zero loop cvt.
//  2. __syncthreads per slab = vmcnt(0) drain — flushed the aw prefetch
//     pipeline at every slab boundary. Now: raw s_barrier + lgkmcnt(0)
//     only (sched_barrier(0)-fenced, m201 pattern).
//  3. aw depth-2 (3-set rotation, all indices literal after unroll) to
//     cover ~200-400cy L2 latency with ~2 K-steps of MFMA.
__global__ __launch_bounds__(512, 2) void fused_kernel(
    const float* __restrict__ inputs, const float* __restrict__ targets,
    const float* __restrict__ bias, const unsigned short* __restrict__ Wp,
    float* __restrict__ out)
{
    __shared__ __align__(16) unsigned short buf[2][1024][8];  // 2 x 16 KiB bf16
    __shared__ float R[8][64][3];                             // 6 KiB
    const int tid  = threadIdx.x;
    const int base = blockIdx.x * 64;
    const int wid  = tid >> 6;
    const int lane = tid & 63;
    const int quad = lane >> 4;
    const int lcol = lane & 15;
    const int ct0  = wid * 5;
    const bf16x8* Wf = (const bf16x8*)Wp;

    // staging map: thread owns chunks (rowA, cch) and (rowB, cch); a chunk
    // is 8 consecutive k (16 B bf16). phys chunk = cch ^ (row & 15).
    const int rowA  = tid >> 4;            // 0..31
    const int rowB  = 32 + (tid >> 4);     // 32..63
    const int cch   = tid & 15;
    const int physA = cch ^ (rowA & 15);
    const int physB = cch ^ (rowB & 15);
    const float* inb = inputs + (size_t)base * DIMK;

    float4 ga0, ga1, gb0, gb1;

#define GLOAD(t) do {                                                         \
    const float* pA_ = inb + (size_t)rowA * DIMK + (t) * 128 + cch * 8;       \
    const float* pB_ = inb + (size_t)rowB * DIMK + (t) * 128 + cch * 8;       \
    ga0 = *(const float4*)pA_; ga1 = *(const float4*)(pA_ + 4);               \
    gb0 = *(const float4*)pB_; gb1 = *(const float4*)(pB_ + 4);               \
} while (0)

#define CVTWRITE(nb) do {                                                     \
    union { __bf16 h[8]; uint4 u; } cA_, cB_;                                 \
    cA_.h[0]=(__bf16)ga0.x; cA_.h[1]=(__bf16)ga0.y;                           \
    cA_.h[2]=(__bf16)ga0.z; cA_.h[3]=(__bf16)ga0.w;                           \
    cA_.h[4]=(__bf16)ga1.x; cA_.h[5]=(__bf16)ga1.y;                           \
    cA_.h[6]=(__bf16)ga1.z; cA_.h[7]=(__bf16)ga1.w;                           \
    cB_.h[0]=(__bf16)gb0.x; cB_.h[1]=(__bf16)gb0.y;                           \
    cB_.h[2]=(__bf16)gb0.z; cB_.h[3]=(__bf16)gb0.w;                           \
    cB_.h[4]=(__bf16)gb1.x; cB_.h[5]=(__bf16)gb1.y;                           \
    cB_.h[6]=(__bf16)gb1.z; cB_.h[7]=(__bf16)gb1.w;                           \
    *(uint4*)&buf[nb][rowA * 16 + physA][0] = cA_.u;                          \
    *(uint4*)&buf[nb][rowB * 16 + physB][0] = cB_.u;                          \
} while (0)

#define LDAW(dst, ksg)                                                        \
    { _Pragma("unroll") for (int t5_ = 0; t5_ < 5; ++t5_)                     \
        dst[t5_] = Wf[((size_t)(ct0 + t5_) * 16 + (ksg)) * 64 + lane]; }

    // B fragment: sample st*16+lcol, k-chunk jl*4+quad (8 consecutive k)
#define LDBS(dst, nb, jl)                                                     \
    { _Pragma("unroll") for (int st_ = 0; st_ < 4; ++st_) {                   \
        int sr_ = st_ * 16 + lcol;                                            \
        dst[st_] = *(const bf16x8*)&buf[nb][sr_ * 16 +                        \
                       (((jl) * 4 + quad) ^ (sr_ & 15))][0]; }  }

#define MFMA20(AW, BS)                                                        \
    __builtin_amdgcn_sched_barrier(0);                                        \
    __builtin_amdgcn_s_setprio(1);                                            \
    { _Pragma("unroll") for (int t5_ = 0; t5_ < 5; ++t5_)                     \
      { _Pragma("unroll") for (int st_ = 0; st_ < 4; ++st_)                   \
          acc[t5_][st_] = __builtin_amdgcn_mfma_f32_16x16x32_bf16(            \
              AW[t5_], BS[st_], acc[t5_][st_], 0, 0, 0); } }                  \
    __builtin_amdgcn_s_setprio(0);                                            \
    __builtin_amdgcn_sched_barrier(0);

#define BARRIER_LGKM()                                                        \
    __builtin_amdgcn_sched_barrier(0);                                        \
    asm volatile("s_waitcnt lgkmcnt(0)" ::: "memory");                        \
    __builtin_amdgcn_sched_barrier(0);                                        \
    __builtin_amdgcn_s_barrier();                                             \
    __builtin_amdgcn_sched_barrier(0);

    floatx4 acc[5][4];
    #pragma unroll
    for (int t5 = 0; t5 < 5; ++t5)
        #pragma unroll
        for (int st = 0; st < 4; ++st) acc[t5][st] = (floatx4){0.f, 0.f, 0.f, 0.f};

    bf16x8 a0[5], a1[5], a2[5], bsA[4], bsB[4];

    // ---- prologue: stage slab 0, preload aw(0..1) ----
    LDAW(a0, 0);
    LDAW(a1, 1);
    GLOAD(0);
    CVTWRITE(0);                       // auto vmcnt wait on g (prologue only)
    __syncthreads();

    // ---- slab 0 (buf 0) ----
    GLOAD(1);
    LDBS(bsA, 0, 0);
    LDAW(a2, 2);  LDBS(bsB, 0, 1);  MFMA20(a0, bsA);
    LDAW(a0, 3);  LDBS(bsA, 0, 2);  MFMA20(a1, bsB);
    LDAW(a1, 4);  LDBS(bsB, 0, 3);  MFMA20(a2, bsA);
    LDAW(a2, 5);                    MFMA20(a0, bsB);
    CVTWRITE(1);
    BARRIER_LGKM();

    // ---- slab 1 (buf 1) ----
    GLOAD(2);
    LDBS(bsA, 1, 0);
    LDAW(a0, 6);  LDBS(bsB, 1, 1);  MFMA20(a1, bsA);
    LDAW(a1, 7);  LDBS(bsA, 1, 2);  MFMA20(a2, bsB);
    LDAW(a2, 8);  LDBS(bsB, 1, 3);  MFMA20(a0, bsA);
    LDAW(a0, 9);                    MFMA20(a1, bsB);
    CVTWRITE(0);
    BARRIER_LGKM();

    // ---- slab 2 (buf 0) ----
    GLOAD(3);
    LDBS(bsA, 0, 0);
    LDAW(a1, 10); LDBS(bsB, 0, 1);  MFMA20(a2, bsA);
    LDAW(a2, 11); LDBS(bsA, 0, 2);  MFMA20(a0, bsB);
    LDAW(a0, 12); LDBS(bsB, 0, 3);  MFMA20(a1, bsA);
    LDAW(a1, 13);                   MFMA20(a2, bsB);
    CVTWRITE(1);
    BARRIER_LGKM();

    // ---- slab 3 (buf 1) ----
    LDBS(bsA, 1, 0);
    LDAW(a2, 14); LDBS(bsB, 1, 1);  MFMA20(a0, bsA);
    LDAW(a0, 15); LDBS(bsA, 1, 2);  MFMA20(a1, bsB);
                  LDBS(bsB, 1, 3);  MFMA20(a2, bsA);
                                    MFMA20(a0, bsB);

    // ---- epilogue: paired re/im cols share one sincos (revolutions) ----
    float xs[4], ys[4];
    #pragma unroll
    for (int st = 0; st < 4; ++st) {
        float2 t2 = *(const float2*)(targets + 2 * (base + st * 16 + lcol));
        xs[st] = 0.5f * t2.x;             // sin(pi*z) = v_sin(z/2 rev)
        ys[st] = 0.5f * t2.y;
    }

    float pd[4]  = {0.f, 0.f, 0.f, 0.f};
    float pr[4]  = {0.f, 0.f, 0.f, 0.f};
    float pim[4] = {0.f, 0.f, 0.f, 0.f};

    #pragma unroll
    for (int t5 = 0; t5 < 5; ++t5)
        #pragma unroll
        for (int p = 0; p < 2; ++p) {
            int colw = (ct0 + t5) * 16 + quad * 4 + 2 * p;   // even slot
            if (colw < NOUT) {
                int jj = colw >> 1;
                int r = jj / 17;
                int c = jj - r * 17;
                float cf = (float)c, rf = (float)r;
                float be = bias[jj];
                float bo = bias[jj + NPARC];
                #pragma unroll
                for (int st = 0; st < 4; ++st) {
                    float ve = acc[t5][st][2 * p]     + be;
                    float vo = acc[t5][st][2 * p + 1] + bo;
                    float u = fmaf(cf, xs[st], rf * ys[st]);
                    u = __builtin_amdgcn_fractf(u);
                    float sn = __builtin_amdgcn_sinf(u);
                    float cs = __builtin_amdgcn_cosf(u);
                    pd[st]  = fmaf(ve, ve, pd[st]);
                    pd[st]  = fmaf(vo, vo, pd[st]);
                    pr[st]  = fmaf(ve, cs, pr[st]);
                    pr[st]  = fmaf(-vo, sn, pr[st]);
                    pim[st] = fmaf(ve, sn, pim[st]);
                    pim[st] = fmaf(vo, cs, pim[st]);
                }
            }
        }

    // fold the 4 quads (weight-col rows) — butterfly on lane bits 4,5
    #pragma unroll
    for (int d = 16; d < 64; d <<= 1)
        #pragma unroll
        for (int st = 0; st < 4; ++st) {
            pd[st]  += __shfl_xor(pd[st], d, 64);
            pr[st]  += __shfl_xor(pr[st], d, 64);
            pim[st] += __shfl_xor(pim[st], d, 64);
        }

    if (lane < 16) {
        #pragma unroll
        for (int st = 0; st < 4; ++st) {
            int sl = st * 16 + lane;
            R[wid][sl][0] = pd[st];
            R[wid][sl][1] = pr[st];
            R[wid][sl][2] = pim[st];
        }
    }
    __syncthreads();

    if (tid < 64) {
        float sd = 0.f, sr = 0.f, si = 0.f;
        #pragma unroll
        for (int w = 0; w < 8; ++w) {
            sd += R[w][tid][0];
            sr += R[w][tid][1];
            si += R[w][tid][2];
        }
        out[base + tid] = (sr * sr + si * si) / (4.0f * sd);
    }
#undef GLOAD
#undef CVTWRITE
#undef LDAW
#undef LDBS
#undef MFMA20
#undef BARRIER_LGKM
}

extern "C" void kernel_launch(void* const* d_in, const int* in_sizes, int n_in,
                              void* d_out, int out_size, void* d_ws, size_t ws_size,
                              hipStream_t stream) {
    const float* inputs  = (const float*)d_in[0];
    const float* targets = (const float*)d_in[1];
    const float* W       = (const float*)d_in[2];
    const float* bias    = (const float*)d_in[3];
    unsigned short* Wp   = (unsigned short*)d_ws;   // 640 KiB of ws

    prep_w<<<160, 256, 0, stream>>>(W, Wp);
    fused_kernel<<<BATCH / 64, 512, 0, stream>>>(inputs, targets, bias, Wp, (float*)d_out);
}